// Round 1
// baseline (314.170 us; speedup 1.0000x reference)
//
#include <hip/hip_runtime.h>
#include <hip/hip_cooperative_groups.h>

namespace cg = cooperative_groups;

// CommNet forward, fp32. B=512, M=32, H=256, NAG=8, NACT=16.
// R10: single cooperative kernel (3 phases + 2 grid.sync) to kill the two
// inter-kernel launch gaps that dominated R8's wall-vs-device-time split.
// Phase A (k_lin): in-block grouping + x staging + DMA weight stream ->
//   acc8 keyed BY EXAMPLE. Phase B (k_hidact): partial-sum + tanh +
//   action/baseline. Phase C (k_out): grouping + hid transpose staging +
//   DMA Wo stream. Phase C's first Wo tile is DMA'd BEFORE sync1 so its
//   latency hides in the barrier; phase B bias loads likewise issue early.
// Kept lessons: DMA dest = wave-uniform base + lane*16B, chunk = 256 floats
// (R5); exactly 2 co-resident blocks/CU (73.2 KB LDS, needed for both the
// vmcnt(0) drain overlap (R7) and the cooperative barrier); no launch_bounds
// min-wave cap (R2 spill); no register streaming (R3/R4). Fallback to the
// verified 3-kernel pipeline if cooperative launch is refused.

constexpr int Bn = 512, Mn = 32, NAGn = 8, Hn = 256, NACTn = 16;
constexpr int On = Hn * NAGn;  // 2048
constexpr int En = 32;         // padded slots/model (counts <= 32: held R1-R9)
constexpr int EW = 8;          // examples per wave
constexpr int XS = 40;         // x LDS stride: %4==0 (aligned b128), 4-way-only write conflicts

__device__ __forceinline__ void gl_lds16(const float* g, float* l) {
  __builtin_amdgcn_global_load_lds(
      (const __attribute__((address_space(1))) void*)g,
      (__attribute__((address_space(3))) void*)l, 16, 0, 0);
}

// build per-model example list in LDS (order nondeterministic; results keyed
// by example so order is irrelevant). All 256 threads must call.
__device__ __forceinline__ void build_group(const int* __restrict__ ids, int m,
                                            int* lst, int* cnt, int tid) {
  if (tid < En) lst[tid] = -1;
  if (tid == 0) *cnt = 0;
  __syncthreads();
  for (int i = tid; i < Bn; i += 256) {
    if (ids[i] == m) {
      int p = atomicAdd(cnt, 1);
      if (p < En) lst[p] = i;
    }
  }
  __syncthreads();
}

// ws: acc8 @0: [8 kc][512 e][256 col] f32 = 4 MB

// ==================== fused cooperative kernel =============================
// grid 512 blocks x 256 thr, 2 blocks/CU (73.2 KB LDS).
// phase A role: ct=bid&1 (128col), kc=(bid>>1)&7 (64k: 0-3 Wc, 4-7 Wr), m=bid>>4
// phase B role: e=bid
// phase C role: ct=bid&15 (128col), m=bid>>4
__global__ __launch_bounds__(256) void k_fused(
    const float* __restrict__ Wc, const float* __restrict__ Wr,
    const float* __restrict__ comm_in, const float* __restrict__ prev_hid,
    const int* __restrict__ ids, float* __restrict__ acc8,
    const float* __restrict__ bc, const float* __restrict__ br,
    const int* __restrict__ inp, const float* __restrict__ lut,
    const float* __restrict__ enc_bias, const float* __restrict__ Wa,
    const float* __restrict__ ba, const float* __restrict__ Wb,
    const float* __restrict__ bb, float* __restrict__ hid,
    float* __restrict__ aprob, float* __restrict__ bl,
    const float* __restrict__ Wo, const float* __restrict__ bo,
    float* __restrict__ comm_out) {
  cg::grid_group grid = cg::this_grid();
  int bid = blockIdx.x;
  int tid = threadIdx.x, w = tid >> 6, lane = tid & 63;
  __shared__ int lst[En];
  __shared__ int cnt;
  __shared__ alignas(16) float xs[Hn * XS];        // 40 KB (phase A uses 10 KB)
  __shared__ alignas(16) float wbuf[2][32 * 128];  // 32 KB (phase C uses 16 KB)
  __shared__ float hs[Hn];                         // 1 KB (phase B only)

  // ---------------- phase A: acc8[kc][e][col] = x-chunk @ {Wc,Wr}-chunk ----
  {
    int ct = bid & 1, kc = (bid >> 1) & 7, m = bid >> 4;
    build_group(ids, m, lst, &cnt, tid);
    if (cnt != 0) {  // block-uniform; all blocks still reach grid.sync below
      int kb = (kc & 3) * 64;
      const float* W = ((kc < 4) ? Wc : Wr) + (size_t)m * Hn * Hn +
                       (size_t)kb * Hn + ct * 128;

      // stage x[k][j] (k local 0..63 = global kb+k); wave w stages its octet.
      int k = lane, j0 = w * EW;
#pragma unroll
      for (int jj = 0; jj < EW; jj++) {
        int j = j0 + jj, e = lst[j];
        float v = 0.f;
        if (e >= 0) {
          if (kc < 4) {
            const float* cp = comm_in + (size_t)e * NAGn * Hn + kb + k;
#pragma unroll
            for (int a = 0; a < NAGn; a++) v += cp[a * Hn];
          } else {
            v = prev_hid[(size_t)e * Hn + kb + k];
          }
        }
        xs[k * XS + j] = v;
      }
      // DMA W tile 0 (rows 0..31): 16 chunks of 2 rows (256 floats)
#pragma unroll
      for (int q = 0; q < 4; q++) {
        int c = w * 4 + q;
        int row = c * 2 + (lane >> 5);
        gl_lds16(W + (size_t)row * Hn + (lane & 31) * 4, wbuf[0] + c * 256);
      }
      float2 acc[EW];
#pragma unroll
      for (int j = 0; j < EW; j++) acc[j] = make_float2(0.f, 0.f);
      __syncthreads();

      for (int t = 0; t < 2; t++) {
        if (t == 0) {
#pragma unroll
          for (int q = 0; q < 4; q++) {
            int c = w * 4 + q;
            int row = 32 + c * 2 + (lane >> 5);
            gl_lds16(W + (size_t)row * Hn + (lane & 31) * 4, wbuf[1] + c * 256);
          }
        }
        const float* wb = wbuf[t] + lane * 2;
        const float* xb = xs + (size_t)(t * 32) * XS + j0;
#pragma unroll 8
        for (int kk = 0; kk < 32; kk++) {
          float2 wv = *(const float2*)(wb + kk * 128);
          float4 xa = *(const float4*)(xb + kk * XS);
          float4 xc = *(const float4*)(xb + kk * XS + 4);
          acc[0].x += xa.x * wv.x; acc[0].y += xa.x * wv.y;
          acc[1].x += xa.y * wv.x; acc[1].y += xa.y * wv.y;
          acc[2].x += xa.z * wv.x; acc[2].y += xa.z * wv.y;
          acc[3].x += xa.w * wv.x; acc[3].y += xa.w * wv.y;
          acc[4].x += xc.x * wv.x; acc[4].y += xc.x * wv.y;
          acc[5].x += xc.y * wv.x; acc[5].y += xc.y * wv.y;
          acc[6].x += xc.z * wv.x; acc[6].y += xc.z * wv.y;
          acc[7].x += xc.w * wv.x; acc[7].y += xc.w * wv.y;
        }
        __syncthreads();
      }
#pragma unroll
      for (int jj = 0; jj < EW; jj++) {
        int e = lst[j0 + jj];
        if (e < 0) continue;
        *(float2*)(acc8 + ((size_t)kc * Bn + e) * Hn + ct * 128 + lane * 2) =
            acc[jj];
      }
    }
  }

  // ---- cross-phase prefetch: phase C's first Wo tile (rows 0..15) into
  // wbuf[0]. wbuf is dead after phase A's final __syncthreads; phase B never
  // touches it. The DMA drains inside grid.sync's fence -> latency hidden. ----
  int ct3 = bid & 15, m3 = bid >> 4;
  const float* wsrc3 = Wo + (size_t)m3 * Hn * On + ct3 * 128;
#pragma unroll
  for (int q = 0; q < 2; q++) {
    int c = w * 2 + q;
    int row = c * 2 + (lane >> 5);
    gl_lds16(wsrc3 + (size_t)row * On + (lane & 31) * 4, wbuf[0] + c * 256);
  }
  // phase B bias loads issued before the barrier too (independent of acc8).
  int m2 = ids[bid];
  float tacc = bc[m2 * Hn + tid] + br[m2 * Hn + tid] + enc_bias[tid] +
               lut[(size_t)inp[bid] * Hn + tid];

  grid.sync();

  // ---------------- phase B: hid = tanh(sum8 + biases); action + baseline --
  {
    int e = bid;
#pragma unroll
    for (int kc = 0; kc < 8; kc++)
      tacc += acc8[((size_t)kc * Bn + e) * Hn + tid];
    float h = tanhf(tacc);
    hid[(size_t)e * Hn + tid] = h;
    hs[tid] = h;
    __syncthreads();
    if (tid < 64) {
      int l = tid, o = l & 15, kk = l >> 4;
      const float* wap = Wa + (size_t)m2 * Hn * NACTn + l;
      float al = 0.f;
      for (int w16 = 0; w16 < 4; w16++) {
        float wv[16], hv[16];
#pragma unroll
        for (int il = 0; il < 16; il++) wv[il] = wap[(w16 * 16 + il) * 64];
#pragma unroll
        for (int il = 0; il < 16; il++) hv[il] = hs[w16 * 64 + il * 4 + kk];
#pragma unroll
        for (int il = 0; il < 16; il++) al += wv[il] * hv[il];
      }
      al += __shfl_xor(al, 16);
      al += __shfl_xor(al, 32);
      al += ba[m2 * NACTn + o];

      float mx = al;
      mx = fmaxf(mx, __shfl_xor(mx, 1));
      mx = fmaxf(mx, __shfl_xor(mx, 2));
      mx = fmaxf(mx, __shfl_xor(mx, 4));
      mx = fmaxf(mx, __shfl_xor(mx, 8));
      float ex = expf(al - mx);
      float sm = ex;
      sm += __shfl_xor(sm, 1);
      sm += __shfl_xor(sm, 2);
      sm += __shfl_xor(sm, 4);
      sm += __shfl_xor(sm, 8);
      if (l < 16) aprob[e * NACTn + l] = ex / sm;

      float pb = 0.f;
      const float* wbp = Wb + (size_t)m2 * Hn;
      {
        float wv[4], hv[4];
#pragma unroll
        for (int k = 0; k < 4; k++) {
          wv[k] = wbp[l + k * 64];
          hv[k] = hs[l + k * 64];
        }
#pragma unroll
        for (int k = 0; k < 4; k++) pb += wv[k] * hv[k];
      }
      pb += __shfl_xor(pb, 1);
      pb += __shfl_xor(pb, 2);
      pb += __shfl_xor(pb, 4);
      pb += __shfl_xor(pb, 8);
      pb += __shfl_xor(pb, 16);
      pb += __shfl_xor(pb, 32);
      if (l == 0) bl[e] = pb + bb[m2];
    }
  }

  grid.sync();

  // ---------------- phase C: comm_out = (hid @ Wo + bo) / 7 ----------------
  {
    int ct = ct3, m = m3;
    build_group(ids, m, lst, &cnt, tid);
    if (cnt != 0) {
      // stage x[k][j] from hid (manual transpose; tid = k)
      for (int j = 0; j < En; j++) {
        int e = lst[j];
        float v = (e >= 0) ? hid[(size_t)e * Hn + tid] : 0.f;
        xs[tid * XS + j] = v;
      }
      // tile 0 already DMA'd into wbuf[0] before sync1.
      int j0 = w * EW;
      float2 acc[EW];
#pragma unroll
      for (int j = 0; j < EW; j++) acc[j] = make_float2(0.f, 0.f);
      __syncthreads();

      for (int t = 0; t < 16; t++) {
        if (t < 15) {
          const float* ws2 = wsrc3 + (size_t)(t + 1) * 16 * On;
#pragma unroll
          for (int q = 0; q < 2; q++) {
            int c = w * 2 + q;
            int row = c * 2 + (lane >> 5);
            gl_lds16(ws2 + (size_t)row * On + (lane & 31) * 4,
                     wbuf[(t + 1) & 1] + c * 256);
          }
        }
        const float* wb = wbuf[t & 1] + lane * 2;
        const float* xb = xs + (size_t)(t * 16) * XS + j0;
#pragma unroll 8
        for (int k = 0; k < 16; k++) {
          float2 wv = *(const float2*)(wb + k * 128);
          float4 xa = *(const float4*)(xb + k * XS);
          float4 xc = *(const float4*)(xb + k * XS + 4);
          acc[0].x += xa.x * wv.x; acc[0].y += xa.x * wv.y;
          acc[1].x += xa.y * wv.x; acc[1].y += xa.y * wv.y;
          acc[2].x += xa.z * wv.x; acc[2].y += xa.z * wv.y;
          acc[3].x += xa.w * wv.x; acc[3].y += xa.w * wv.y;
          acc[4].x += xc.x * wv.x; acc[4].y += xc.x * wv.y;
          acc[5].x += xc.y * wv.x; acc[5].y += xc.y * wv.y;
          acc[6].x += xc.z * wv.x; acc[6].y += xc.z * wv.y;
          acc[7].x += xc.w * wv.x; acc[7].y += xc.w * wv.y;
        }
        __syncthreads();
      }
      float2 bv = *(const float2*)(bo + (size_t)m * On + ct * 128 + lane * 2);
      const float inv = 1.f / 7.f;
#pragma unroll
      for (int jj = 0; jj < EW; jj++) {
        int e = lst[j0 + jj];
        if (e < 0) continue;
        float2 o;
        o.x = (acc[jj].x + bv.x) * inv;
        o.y = (acc[jj].y + bv.y) * inv;
        *(float2*)(comm_out + (size_t)e * On + ct * 128 + lane * 2) = o;
      }
    }
  }
}

// ==================== fallback: verified R9 3-kernel pipeline ==============

__global__ __launch_bounds__(256) void k_lin(
    const float* __restrict__ Wc, const float* __restrict__ Wr,
    const float* __restrict__ comm_in, const float* __restrict__ prev_hid,
    const int* __restrict__ ids, float* __restrict__ acc8) {
  int ct = blockIdx.x, kc = blockIdx.y, m = blockIdx.z;
  int tid = threadIdx.x, w = tid >> 6, lane = tid & 63;
  __shared__ int lst[En];
  __shared__ int cnt;
  __shared__ alignas(16) float xs[64 * XS];
  __shared__ alignas(16) float wbuf[2][32 * 128];

  build_group(ids, m, lst, &cnt, tid);
  if (cnt == 0) return;

  int kb = (kc & 3) * 64;
  const float* W = ((kc < 4) ? Wc : Wr) + (size_t)m * Hn * Hn + (size_t)kb * Hn + ct * 128;

  int k = lane, j0 = w * EW;
#pragma unroll
  for (int jj = 0; jj < EW; jj++) {
    int j = j0 + jj, e = lst[j];
    float v = 0.f;
    if (e >= 0) {
      if (kc < 4) {
        const float* cp = comm_in + (size_t)e * NAGn * Hn + kb + k;
#pragma unroll
        for (int a = 0; a < NAGn; a++) v += cp[a * Hn];
      } else {
        v = prev_hid[(size_t)e * Hn + kb + k];
      }
    }
    xs[k * XS + j] = v;
  }
#pragma unroll
  for (int q = 0; q < 4; q++) {
    int c = w * 4 + q;
    int row = c * 2 + (lane >> 5);
    gl_lds16(W + (size_t)row * Hn + (lane & 31) * 4, wbuf[0] + c * 256);
  }
  float2 acc[EW];
#pragma unroll
  for (int j = 0; j < EW; j++) acc[j] = make_float2(0.f, 0.f);
  __syncthreads();

  for (int t = 0; t < 2; t++) {
    if (t == 0) {
#pragma unroll
      for (int q = 0; q < 4; q++) {
        int c = w * 4 + q;
        int row = 32 + c * 2 + (lane >> 5);
        gl_lds16(W + (size_t)row * Hn + (lane & 31) * 4, wbuf[1] + c * 256);
      }
    }
    const float* wb = wbuf[t] + lane * 2;
    const float* xb = xs + (size_t)(t * 32) * XS + j0;
#pragma unroll 8
    for (int kk = 0; kk < 32; kk++) {
      float2 wv = *(const float2*)(wb + kk * 128);
      float4 xa = *(const float4*)(xb + kk * XS);
      float4 xc = *(const float4*)(xb + kk * XS + 4);
      acc[0].x += xa.x * wv.x; acc[0].y += xa.x * wv.y;
      acc[1].x += xa.y * wv.x; acc[1].y += xa.y * wv.y;
      acc[2].x += xa.z * wv.x; acc[2].y += xa.z * wv.y;
      acc[3].x += xa.w * wv.x; acc[3].y += xa.w * wv.y;
      acc[4].x += xc.x * wv.x; acc[4].y += xc.x * wv.y;
      acc[5].x += xc.y * wv.x; acc[5].y += xc.y * wv.y;
      acc[6].x += xc.z * wv.x; acc[6].y += xc.z * wv.y;
      acc[7].x += xc.w * wv.x; acc[7].y += xc.w * wv.y;
    }
    __syncthreads();
  }
#pragma unroll
  for (int jj = 0; jj < EW; jj++) {
    int e = lst[j0 + jj];
    if (e < 0) continue;
    *(float2*)(acc8 + ((size_t)kc * Bn + e) * Hn + ct * 128 + lane * 2) = acc[jj];
  }
}

__global__ __launch_bounds__(256) void k_hidact(
    const float* __restrict__ acc8, const float* __restrict__ bc,
    const float* __restrict__ br, const int* __restrict__ inp,
    const float* __restrict__ lut, const float* __restrict__ enc_bias,
    const int* __restrict__ ids, const float* __restrict__ Wa,
    const float* __restrict__ ba, const float* __restrict__ Wb,
    const float* __restrict__ bb, float* __restrict__ hid,
    float* __restrict__ aprob, float* __restrict__ bl) {
  int e = blockIdx.x, tid = threadIdx.x;
  int m = ids[e];
  __shared__ float hs[Hn];
  float t = bc[m * Hn + tid] + br[m * Hn + tid] + enc_bias[tid] +
            lut[(size_t)inp[e] * Hn + tid];
#pragma unroll
  for (int kc = 0; kc < 8; kc++)
    t += acc8[((size_t)kc * Bn + e) * Hn + tid];
  float h = tanhf(t);
  hid[(size_t)e * Hn + tid] = h;
  hs[tid] = h;
  __syncthreads();
  if (tid < 64) {
    int l = tid, o = l & 15, kk = l >> 4;
    const float* wap = Wa + (size_t)m * Hn * NACTn + l;
    float al = 0.f;
    for (int w16 = 0; w16 < 4; w16++) {
      float wv[16], hv[16];
#pragma unroll
      for (int il = 0; il < 16; il++) wv[il] = wap[(w16 * 16 + il) * 64];
#pragma unroll
      for (int il = 0; il < 16; il++) hv[il] = hs[w16 * 64 + il * 4 + kk];
#pragma unroll
      for (int il = 0; il < 16; il++) al += wv[il] * hv[il];
    }
    al += __shfl_xor(al, 16);
    al += __shfl_xor(al, 32);
    al += ba[m * NACTn + o];

    float mx = al;
    mx = fmaxf(mx, __shfl_xor(mx, 1));
    mx = fmaxf(mx, __shfl_xor(mx, 2));
    mx = fmaxf(mx, __shfl_xor(mx, 4));
    mx = fmaxf(mx, __shfl_xor(mx, 8));
    float ex = expf(al - mx);
    float sm = ex;
    sm += __shfl_xor(sm, 1);
    sm += __shfl_xor(sm, 2);
    sm += __shfl_xor(sm, 4);
    sm += __shfl_xor(sm, 8);
    if (l < 16) aprob[e * NACTn + l] = ex / sm;

    float pb = 0.f;
    const float* wbp = Wb + (size_t)m * Hn;
    {
      float wv[4], hv[4];
#pragma unroll
      for (int k = 0; k < 4; k++) { wv[k] = wbp[l + k * 64]; hv[k] = hs[l + k * 64]; }
#pragma unroll
      for (int k = 0; k < 4; k++) pb += wv[k] * hv[k];
    }
    pb += __shfl_xor(pb, 1);
    pb += __shfl_xor(pb, 2);
    pb += __shfl_xor(pb, 4);
    pb += __shfl_xor(pb, 8);
    pb += __shfl_xor(pb, 16);
    pb += __shfl_xor(pb, 32);
    if (l == 0) bl[e] = pb + bb[m];
  }
}

__global__ __launch_bounds__(256) void k_out(
    const float* __restrict__ Wo, const float* __restrict__ hid,
    const float* __restrict__ bo, const int* __restrict__ ids,
    float* __restrict__ comm_out) {
  int ct = blockIdx.x, m = blockIdx.y;
  int tid = threadIdx.x, w = tid >> 6, lane = tid & 63;
  __shared__ int lst[En];
  __shared__ int cnt;
  __shared__ alignas(16) float xs[Hn * XS];
  __shared__ alignas(16) float wbuf[2][16 * 128];

  build_group(ids, m, lst, &cnt, tid);
  if (cnt == 0) return;

  for (int j = 0; j < En; j++) {
    int e = lst[j];
    float v = (e >= 0) ? hid[(size_t)e * Hn + tid] : 0.f;
    xs[tid * XS + j] = v;
  }
  const float* wsrc = Wo + (size_t)m * Hn * On + ct * 128;
#pragma unroll
  for (int q = 0; q < 2; q++) {
    int c = w * 2 + q;
    int row = c * 2 + (lane >> 5);
    gl_lds16(wsrc + (size_t)row * On + (lane & 31) * 4, wbuf[0] + c * 256);
  }
  int j0 = w * EW;
  float2 acc[EW];
#pragma unroll
  for (int j = 0; j < EW; j++) acc[j] = make_float2(0.f, 0.f);
  __syncthreads();

  for (int t = 0; t < 16; t++) {
    if (t < 15) {
      const float* ws2 = wsrc + (size_t)(t + 1) * 16 * On;
#pragma unroll
      for (int q = 0; q < 2; q++) {
        int c = w * 2 + q;
        int row = c * 2 + (lane >> 5);
        gl_lds16(ws2 + (size_t)row * On + (lane & 31) * 4, wbuf[(t + 1) & 1] + c * 256);
      }
    }
    const float* wb = wbuf[t & 1] + lane * 2;
    const float* xb = xs + (size_t)(t * 16) * XS + j0;
#pragma unroll 8
    for (int k = 0; k < 16; k++) {
      float2 wv = *(const float2*)(wb + k * 128);
      float4 xa = *(const float4*)(xb + k * XS);
      float4 xc = *(const float4*)(xb + k * XS + 4);
      acc[0].x += xa.x * wv.x; acc[0].y += xa.x * wv.y;
      acc[1].x += xa.y * wv.x; acc[1].y += xa.y * wv.y;
      acc[2].x += xa.z * wv.x; acc[2].y += xa.z * wv.y;
      acc[3].x += xa.w * wv.x; acc[3].y += xa.w * wv.y;
      acc[4].x += xc.x * wv.x; acc[4].y += xc.x * wv.y;
      acc[5].x += xc.y * wv.x; acc[5].y += xc.y * wv.y;
      acc[6].x += xc.z * wv.x; acc[6].y += xc.z * wv.y;
      acc[7].x += xc.w * wv.x; acc[7].y += xc.w * wv.y;
    }
    __syncthreads();
  }
  float2 bv = *(const float2*)(bo + (size_t)m * On + ct * 128 + lane * 2);
  const float inv = 1.f / 7.f;
#pragma unroll
  for (int jj = 0; jj < EW; jj++) {
    int e = lst[j0 + jj];
    if (e < 0) continue;
    float2 o;
    o.x = (acc[jj].x + bv.x) * inv;
    o.y = (acc[jj].y + bv.y) * inv;
    *(float2*)(comm_out + (size_t)e * On + ct * 128 + lane * 2) = o;
  }
}

extern "C" void kernel_launch(void* const* d_in, const int* in_sizes, int n_in,
                              void* d_out, int out_size, void* d_ws, size_t ws_size,
                              hipStream_t stream) {
  const float* comm_in  = (const float*)d_in[0];
  const int*   inp      = (const int*)d_in[1];
  const float* prev_hid = (const float*)d_in[2];
  const int*   ids      = (const int*)d_in[4];
  const float* Wc = (const float*)d_in[5];
  const float* bc = (const float*)d_in[6];
  const float* Wr = (const float*)d_in[7];
  const float* br = (const float*)d_in[8];
  const float* Wa = (const float*)d_in[9];
  const float* ba = (const float*)d_in[10];
  const float* Wb = (const float*)d_in[11];
  const float* bb = (const float*)d_in[12];
  const float* Wo = (const float*)d_in[13];
  const float* bo = (const float*)d_in[14];
  const float* lut      = (const float*)d_in[15];
  const float* enc_bias = (const float*)d_in[16];

  float* out      = (float*)d_out;
  float* aprob    = out;                     // [512,16]
  float* bl       = out + Bn * NACTn;        // [512]
  float* hid      = out + Bn * NACTn + Bn;   // [512,256]
  float* comm_out = hid + Bn * Hn;           // [512,2048]

  float* acc8 = (float*)d_ws;                // [8][512][256] = 4 MB

  void* args[] = {
      (void*)&Wc, (void*)&Wr, (void*)&comm_in, (void*)&prev_hid, (void*)&ids,
      (void*)&acc8, (void*)&bc, (void*)&br, (void*)&inp, (void*)&lut,
      (void*)&enc_bias, (void*)&Wa, (void*)&ba, (void*)&Wb, (void*)&bb,
      (void*)&hid, (void*)&aprob, (void*)&bl, (void*)&Wo, (void*)&bo,
      (void*)&comm_out};
  hipError_t err = hipLaunchCooperativeKernel(
      (const void*)k_fused, dim3(512), dim3(256), args, 0, stream);
  if (err != hipSuccess) {
    (void)hipGetLastError();  // clear; fall back to verified 3-kernel path
    k_lin<<<dim3(2, 8, Mn), 256, 0, stream>>>(Wc, Wr, comm_in, prev_hid, ids, acc8);
    k_hidact<<<Bn, 256, 0, stream>>>(acc8, bc, br, inp, lut, enc_bias, ids,
                                     Wa, ba, Wb, bb, hid, aprob, bl);
    k_out<<<dim3(16, Mn), 256, 0, stream>>>(Wo, hid, bo, ids, comm_out);
  }
}

// Round 2
// 185.762 us; speedup vs baseline: 1.6912x; 1.6912x over previous
//
#include <hip/hip_runtime.h>

// CommNet forward, fp32. B=512, M=32, H=256, NAG=8, NACT=16.
// R11: revert R10 cooperative fusion (grid.sync cost ~60us device + ~100us
// graph-replay overhead; VALUBusy 7.7% = spin). Back to plain pipeline, now
// 2 kernels:
//   k_lin  - unchanged math; counted-vmcnt restructure (raw s_barrier +
//            s_waitcnt vmcnt(4)/(0)) so tile-1 DMA is not drained before
//            tile-0 compute.
//   k_outh - k_out + k_hidact merged: each (ct,m) block recomputes hid for
//            its <=32 examples from acc8 straight into xs (kills the
//            hid-read transpose AND one launch gap); ct==0 blocks write
//            hid/aprob/bl. Wo stream uses 3-buffer depth-2 DMA pipeline
//            with counted vmcnt (never 0 in steady state) + dual raw
//            barriers per tile.
// Kept lessons: DMA dest = wave-uniform base + lane*16B, chunk = 256 floats
// (R5); 2 co-resident blocks/CU (65.7 KB LDS) for drain overlap (R7); no
// launch_bounds min-wave cap (R2 spill); no register streaming (R3/R4);
// results keyed by example, slot order irrelevant (R9); no cooperative
// launch (R10).

constexpr int Bn = 512, Mn = 32, NAGn = 8, Hn = 256, NACTn = 16;
constexpr int On = Hn * NAGn;  // 2048
constexpr int En = 32;         // padded slots/model (counts <= 32: held R1-R10)
constexpr int EW = 8;          // examples per wave
constexpr int XS = 40;         // x LDS stride: %4==0 (aligned b128), 4-way-only write conflicts

__device__ __forceinline__ void gl_lds16(const float* g, float* l) {
  __builtin_amdgcn_global_load_lds(
      (const __attribute__((address_space(1))) void*)g,
      (__attribute__((address_space(3))) void*)l, 16, 0, 0);
}

// build per-model example list in LDS (order nondeterministic; results keyed
// by example so order is irrelevant). All 256 threads must call.
__device__ __forceinline__ void build_group(const int* __restrict__ ids, int m,
                                            int* lst, int* cnt, int tid) {
  if (tid < En) lst[tid] = -1;
  if (tid == 0) *cnt = 0;
  __syncthreads();
  for (int i = tid; i < Bn; i += 256) {
    if (ids[i] == m) {
      int p = atomicAdd(cnt, 1);
      if (p < En) lst[p] = i;
    }
  }
  __syncthreads();
}

// ws: acc8 @0: [8 kc][512 e][256 col] f32 = 4 MB

// -------- kernel 1: acc8[kc][e][col] = x-chunk @ {Wc,Wr}-chunk --------------
// grid (2 ct[128col], 8 kc[64k: 0-3 Wc, 4-7 Wr], 32 m) = 512 blocks, 2/CU.
__global__ __launch_bounds__(256) void k_lin(
    const float* __restrict__ Wc, const float* __restrict__ Wr,
    const float* __restrict__ comm_in, const float* __restrict__ prev_hid,
    const int* __restrict__ ids, float* __restrict__ acc8) {
  int ct = blockIdx.x, kc = blockIdx.y, m = blockIdx.z;
  int tid = threadIdx.x, w = tid >> 6, lane = tid & 63;
  __shared__ int lst[En];
  __shared__ int cnt;
  __shared__ alignas(16) float xs[64 * XS];        // 10 KB
  __shared__ alignas(16) float wbuf[2][32 * 128];  // 32 KB

  build_group(ids, m, lst, &cnt, tid);
  if (cnt == 0) return;

  int kb = (kc & 3) * 64;
  const float* W = ((kc < 4) ? Wc : Wr) + (size_t)m * Hn * Hn + (size_t)kb * Hn + ct * 128;

  // stage x[k][j] (k local 0..63 = global kb+k); wave w stages its own octet.
  int k = lane, j0 = w * EW;
#pragma unroll
  for (int jj = 0; jj < EW; jj++) {
    int j = j0 + jj, e = lst[j];
    float v = 0.f;
    if (e >= 0) {
      if (kc < 4) {
        const float* cp = comm_in + (size_t)e * NAGn * Hn + kb + k;
#pragma unroll
        for (int a = 0; a < NAGn; a++) v += cp[a * Hn];
      } else {
        v = prev_hid[(size_t)e * Hn + kb + k];
      }
    }
    xs[k * XS + j] = v;
  }
  // issue BOTH W tiles up front (4 chunks of 2 rows each per wave per tile)
#pragma unroll
  for (int q = 0; q < 4; q++) {
    int c = w * 4 + q;
    int row = c * 2 + (lane >> 5);
    gl_lds16(W + (size_t)row * Hn + (lane & 31) * 4, wbuf[0] + c * 256);
  }
#pragma unroll
  for (int q = 0; q < 4; q++) {
    int c = w * 4 + q;
    int row = 32 + c * 2 + (lane >> 5);
    gl_lds16(W + (size_t)row * Hn + (lane & 31) * 4, wbuf[1] + c * 256);
  }
  float2 acc[EW];
#pragma unroll
  for (int j = 0; j < EW; j++) acc[j] = make_float2(0.f, 0.f);

#pragma unroll
  for (int t = 0; t < 2; t++) {
    // counted wait: own tile-t loads done (4 newest = tile t+1 may fly on);
    // lgkmcnt(0) on t=0 makes xs stores visible. Raw barrier: no vmcnt(0)
    // drain of the other tile's DMA.
    if (t == 0)
      asm volatile("s_waitcnt vmcnt(4) lgkmcnt(0)" ::: "memory");
    else
      asm volatile("s_waitcnt vmcnt(0)" ::: "memory");
    __builtin_amdgcn_s_barrier();
    const float* wb = wbuf[t] + lane * 2;
    const float* xb = xs + (size_t)(t * 32) * XS + j0;
#pragma unroll 8
    for (int kk = 0; kk < 32; kk++) {
      float2 wv = *(const float2*)(wb + kk * 128);
      float4 xa = *(const float4*)(xb + kk * XS);
      float4 xc = *(const float4*)(xb + kk * XS + 4);
      acc[0].x += xa.x * wv.x; acc[0].y += xa.x * wv.y;
      acc[1].x += xa.y * wv.x; acc[1].y += xa.y * wv.y;
      acc[2].x += xa.z * wv.x; acc[2].y += xa.z * wv.y;
      acc[3].x += xa.w * wv.x; acc[3].y += xa.w * wv.y;
      acc[4].x += xc.x * wv.x; acc[4].y += xc.x * wv.y;
      acc[5].x += xc.y * wv.x; acc[5].y += xc.y * wv.y;
      acc[6].x += xc.z * wv.x; acc[6].y += xc.z * wv.y;
      acc[7].x += xc.w * wv.x; acc[7].y += xc.w * wv.y;
    }
    // no trailing barrier needed: 2 tiles, 2 buffers, no reuse.
  }
#pragma unroll
  for (int jj = 0; jj < EW; jj++) {
    int e = lst[j0 + jj];
    if (e < 0) continue;
    *(float2*)(acc8 + ((size_t)kc * Bn + e) * Hn + ct * 128 + lane * 2) = acc[jj];
  }
}

// -------- kernel 2: hid/action/baseline + comm_out, merged ------------------
// grid (16 ct[128col], 32 m) = 512 blocks; 65.7 KB LDS -> 2/CU.
// Each block recomputes hid for its examples from acc8 (16x redundant acc8
// reads = ~64 MB L2/L3, overlapped with Wo DMA issued first). ct==0 blocks
// also write hid/aprob/bl. Wo stream: 16-row tiles, 3 buffers, depth-2
// prefetch, counted vmcnt + dual raw barriers.
__global__ __launch_bounds__(256) void k_outh(
    const float* __restrict__ Wo, const float* __restrict__ bo,
    const float* __restrict__ acc8, const int* __restrict__ ids,
    const int* __restrict__ inp, const float* __restrict__ lut,
    const float* __restrict__ enc_bias, const float* __restrict__ bc,
    const float* __restrict__ br, const float* __restrict__ Wa,
    const float* __restrict__ ba, const float* __restrict__ Wb,
    const float* __restrict__ bb, float* __restrict__ hid,
    float* __restrict__ aprob, float* __restrict__ bl,
    float* __restrict__ comm_out) {
  int ct = blockIdx.x, m = blockIdx.y;
  int tid = threadIdx.x, w = tid >> 6, lane = tid & 63;
  __shared__ int lst[En];
  __shared__ int cnt;
  __shared__ alignas(16) float xs[Hn * XS];        // 40 KB
  __shared__ alignas(16) float wbuf[3][16 * 128];  // 24 KB

  build_group(ids, m, lst, &cnt, tid);
  if (cnt == 0) return;

  // issue Wo tiles 0 and 1 FIRST: their latency hides under hid compute.
  const float* wsrc = Wo + (size_t)m * Hn * On + ct * 128;
#pragma unroll
  for (int tt = 0; tt < 2; tt++) {
#pragma unroll
    for (int q = 0; q < 2; q++) {
      int c = w * 2 + q;
      int row = tt * 16 + c * 2 + (lane >> 5);
      gl_lds16(wsrc + (size_t)row * On + (lane & 31) * 4, wbuf[tt] + c * 256);
    }
  }

  // hid = tanh(biases + sum_kc acc8) recomputed into xs (thread tid = col k).
  float base = bc[m * Hn + tid] + br[m * Hn + tid] + enc_bias[tid];
  for (int j = 0; j < En; j++) {
    int e = lst[j];  // uniform across block
    float h = 0.f;
    if (e >= 0) {
      float t = base + lut[(size_t)inp[e] * Hn + tid];
#pragma unroll
      for (int kc = 0; kc < 8; kc++)
        t += acc8[((size_t)kc * Bn + e) * Hn + tid];
      h = tanhf(t);
      if (ct == 0) hid[(size_t)e * Hn + tid] = h;
    }
    xs[tid * XS + j] = h;
  }
  // staging barrier: lgkm only (do NOT drain the in-flight Wo DMA).
  asm volatile("s_waitcnt lgkmcnt(0)" ::: "memory");
  __builtin_amdgcn_s_barrier();

  // action softmax + baseline: ct==0 blocks only; wave w owns slots
  // j0..j0+7 independently (shuffle-only reductions, no block sync).
  if (ct == 0) {
    int jb = w * EW;
#pragma unroll
    for (int jj = 0; jj < EW; jj++) {
      int j = jb + jj, e = lst[j];
      if (e < 0) continue;
      int l = lane, o = l & 15, kk = l >> 4;
      const float* wap = Wa + (size_t)m * Hn * NACTn + l;
      float al = 0.f;
      for (int w16 = 0; w16 < 4; w16++) {
        float wv[16], hv[16];
#pragma unroll
        for (int il = 0; il < 16; il++) wv[il] = wap[(w16 * 16 + il) * 64];
#pragma unroll
        for (int il = 0; il < 16; il++)
          hv[il] = xs[(w16 * 64 + il * 4 + kk) * XS + j];
#pragma unroll
        for (int il = 0; il < 16; il++) al += wv[il] * hv[il];
      }
      al += __shfl_xor(al, 16);
      al += __shfl_xor(al, 32);
      al += ba[m * NACTn + o];

      float mx = al;
      mx = fmaxf(mx, __shfl_xor(mx, 1));
      mx = fmaxf(mx, __shfl_xor(mx, 2));
      mx = fmaxf(mx, __shfl_xor(mx, 4));
      mx = fmaxf(mx, __shfl_xor(mx, 8));
      float ex = expf(al - mx);
      float sm = ex;
      sm += __shfl_xor(sm, 1);
      sm += __shfl_xor(sm, 2);
      sm += __shfl_xor(sm, 4);
      sm += __shfl_xor(sm, 8);
      if (l < 16) aprob[e * NACTn + l] = ex / sm;

      float pb = 0.f;
      const float* wbp = Wb + (size_t)m * Hn;
      {
        float wv[4], hv[4];
#pragma unroll
        for (int k2 = 0; k2 < 4; k2++) {
          wv[k2] = wbp[l + k2 * 64];
          hv[k2] = xs[(l + k2 * 64) * XS + j];
        }
#pragma unroll
        for (int k2 = 0; k2 < 4; k2++) pb += wv[k2] * hv[k2];
      }
      pb += __shfl_xor(pb, 1);
      pb += __shfl_xor(pb, 2);
      pb += __shfl_xor(pb, 4);
      pb += __shfl_xor(pb, 8);
      pb += __shfl_xor(pb, 16);
      pb += __shfl_xor(pb, 32);
      if (l == 0) bl[e] = pb + bb[m];
    }
  }

  // Wo stream: 16 tiles x 16 rows; depth-2 prefetch, counted vmcnt.
  int j0 = w * EW;
  float2 acc[EW];
#pragma unroll
  for (int j = 0; j < EW; j++) acc[j] = make_float2(0.f, 0.f);

  for (int t = 0; t < 16; t++) {
    if (t < 14) {
      const float* ws2 = wsrc + (size_t)(t + 2) * 16 * On;
#pragma unroll
      for (int q = 0; q < 2; q++) {
        int c = w * 2 + q;
        int row = c * 2 + (lane >> 5);
        gl_lds16(ws2 + (size_t)row * On + (lane & 31) * 4,
                 wbuf[(t + 2) % 3] + c * 256);
      }
      // own outstanding: tiles t,t+1,t+2 = 6 loads; leave newest 4 in flight.
      asm volatile("s_waitcnt vmcnt(4)" ::: "memory");
    } else if (t == 14) {
      asm volatile("s_waitcnt vmcnt(2)" ::: "memory");
    } else {
      asm volatile("s_waitcnt vmcnt(0)" ::: "memory");
    }
    __builtin_amdgcn_s_barrier();  // all waves' tile-t chunks landed
    const float* wb = wbuf[t % 3] + lane * 2;
    const float* xb = xs + (size_t)(t * 16) * XS + j0;
#pragma unroll 8
    for (int k = 0; k < 16; k++) {
      float2 wv = *(const float2*)(wb + k * 128);
      float4 xa = *(const float4*)(xb + k * XS);
      float4 xc = *(const float4*)(xb + k * XS + 4);
      acc[0].x += xa.x * wv.x; acc[0].y += xa.x * wv.y;
      acc[1].x += xa.y * wv.x; acc[1].y += xa.y * wv.y;
      acc[2].x += xa.z * wv.x; acc[2].y += xa.z * wv.y;
      acc[3].x += xa.w * wv.x; acc[3].y += xa.w * wv.y;
      acc[4].x += xc.x * wv.x; acc[4].y += xc.x * wv.y;
      acc[5].x += xc.y * wv.x; acc[5].y += xc.y * wv.y;
      acc[6].x += xc.z * wv.x; acc[6].y += xc.z * wv.y;
      acc[7].x += xc.w * wv.x; acc[7].y += xc.w * wv.y;
    }
    // trailing barrier: wbuf[t%3] is the DMA target at iter t+1 ((t+3)%3).
    __builtin_amdgcn_s_barrier();
  }
  float2 bv = *(const float2*)(bo + (size_t)m * On + ct * 128 + lane * 2);
  const float inv = 1.f / 7.f;
#pragma unroll
  for (int jj = 0; jj < EW; jj++) {
    int e = lst[j0 + jj];
    if (e < 0) continue;
    float2 o;
    o.x = (acc[jj].x + bv.x) * inv;
    o.y = (acc[jj].y + bv.y) * inv;
    *(float2*)(comm_out + (size_t)e * On + ct * 128 + lane * 2) = o;
  }
}

extern "C" void kernel_launch(void* const* d_in, const int* in_sizes, int n_in,
                              void* d_out, int out_size, void* d_ws, size_t ws_size,
                              hipStream_t stream) {
  const float* comm_in  = (const float*)d_in[0];
  const int*   inp      = (const int*)d_in[1];
  const float* prev_hid = (const float*)d_in[2];
  const int*   ids      = (const int*)d_in[4];
  const float* Wc = (const float*)d_in[5];
  const float* bc = (const float*)d_in[6];
  const float* Wr = (const float*)d_in[7];
  const float* br = (const float*)d_in[8];
  const float* Wa = (const float*)d_in[9];
  const float* ba = (const float*)d_in[10];
  const float* Wb = (const float*)d_in[11];
  const float* bb = (const float*)d_in[12];
  const float* Wo = (const float*)d_in[13];
  const float* bo = (const float*)d_in[14];
  const float* lut      = (const float*)d_in[15];
  const float* enc_bias = (const float*)d_in[16];

  float* out      = (float*)d_out;
  float* aprob    = out;                     // [512,16]
  float* bl       = out + Bn * NACTn;        // [512]
  float* hid      = out + Bn * NACTn + Bn;   // [512,256]
  float* comm_out = hid + Bn * Hn;           // [512,2048]

  float* acc8 = (float*)d_ws;                // [8][512][256] = 4 MB

  k_lin<<<dim3(2, 8, Mn), 256, 0, stream>>>(Wc, Wr, comm_in, prev_hid, ids, acc8);
  k_outh<<<dim3(16, Mn), 256, 0, stream>>>(Wo, bo, acc8, ids, inp, lut, enc_bias,
                                           bc, br, Wa, ba, Wb, bb,
                                           hid, aprob, bl, comm_out);
}

// Round 5
// 180.647 us; speedup vs baseline: 1.7391x; 1.0283x over previous
//
#include <hip/hip_runtime.h>

// CommNet forward, fp32. B=512, M=32, H=256, NAG=8, NACT=16.
// R14: fix R12/R13 correctness. Real bug (not a race): atomicAdd-built lst
// has a DIFFERENT nondeterministic slot order per block, so the "balanced"
// softmax (block ct owns slots {ct, ct+16}) left most examples uncovered ->
// aprob rows stayed 0 (absmax ~0.12 = max softmax prob). Fix: deterministic
// ballot-based grouping (rank by example index) -> lst identical in every
// block -> slot distribution covers each example exactly once.
// Structure kept from R13:
//   k_linh - full K=512 stacked GEMM -> hid=tanh(...); 4 distinct W buffers,
//            single __syncthreads full drain, no trailing-barrier hazard.
//   k_outh - hid staging + balanced softmax + Wo stream (3-buf counted
//            vmcnt, dual raw barrier, sched_barrier pins).
// Kept lessons: DMA dest = wave-uniform base + lane*16B (R5); no
// launch_bounds min-wave cap (R2); no register streaming (R3/R4); no
// cooperative launch (R10); no acc8 round-trip (R12 structure).

constexpr int Bn = 512, Mn = 32, NAGn = 8, Hn = 256, NACTn = 16;
constexpr int On = Hn * NAGn;  // 2048
constexpr int En = 32;         // padded slots/model (counts <= 32: held R1-R13)
constexpr int EW = 8;          // examples per wave
constexpr int XS = 40;         // k_outh x stride (16B-aligned float4 rows)
constexpr int XS2 = 36;        // k_linh x stride: 36*4=144B, %16==0 -> aligned b128

__device__ __forceinline__ void gl_lds16(const float* g, float* l) {
  __builtin_amdgcn_global_load_lds(
      (const __attribute__((address_space(1))) void*)g,
      (__attribute__((address_space(3))) void*)l, 16, 0, 0);
}

// Deterministic per-model example list: slot j = j-th example (by index e)
// with ids[e]==m. Identical in every block. Returns count. All 256 threads
// must call; two internal __syncthreads.
__device__ __forceinline__ int build_group_det(const int* __restrict__ ids,
                                               int m, int* lst, int* segc,
                                               int tid) {
  int w = tid >> 6, lane = tid & 63;
  if (tid < En) lst[tid] = -1;
  unsigned long long msk[2];
#pragma unroll
  for (int p = 0; p < 2; p++) {
    int i = (w * 2 + p) * 64 + lane;
    msk[p] = __ballot(ids[i] == m);
  }
  if (lane == 0) {
    segc[w * 2 + 0] = __popcll(msk[0]);
    segc[w * 2 + 1] = __popcll(msk[1]);
  }
  __syncthreads();
  int tot = 0;
#pragma unroll
  for (int q = 0; q < 8; q++) tot += segc[q];
#pragma unroll
  for (int p = 0; p < 2; p++) {
    int s = w * 2 + p;
    int pre = 0;
    for (int q = 0; q < 8; q++)
      if (q < s) pre += segc[q];
    int i = s * 64 + lane;
    if ((msk[p] >> lane) & 1ull) {
      int rank = pre + __popcll(msk[p] & ((1ull << lane) - 1ull));
      if (rank < En) lst[rank] = i;
    }
  }
  __syncthreads();
  return tot;
}

// -------- kernel 1: hid = tanh([comm-sum; prev_hid] @ [Wc; Wr] + biases) ----
// grid (32 m, 8 ct[32col]) = 256 blocks x 256 thr; 138 KB LDS -> 1/CU.
__global__ __launch_bounds__(256) void k_linh(
    const float* __restrict__ Wc, const float* __restrict__ Wr,
    const float* __restrict__ comm_in, const float* __restrict__ prev_hid,
    const int* __restrict__ ids, const int* __restrict__ inp,
    const float* __restrict__ lut, const float* __restrict__ enc_bias,
    const float* __restrict__ bc, const float* __restrict__ br,
    float* __restrict__ hid) {
  int m = blockIdx.x, ct = blockIdx.y;
  int tid = threadIdx.x, w = tid >> 6, lane = tid & 63;
  __shared__ int lst[En];
  __shared__ int segc[8];
  __shared__ alignas(16) float xs[512 * XS2];      // 73.7 KB: stacked K rows
  __shared__ alignas(16) float wbuf[4][128 * 32];  // 64 KB: 4 distinct tiles

  int cnt = build_group_det(ids, m, lst, segc, tid);
  if (cnt == 0) return;

  // DMA issue for stacked-W tile t (t0,t1 = Wc rows 0..127/128..255;
  // t2,t3 = Wr same). Tile = 16 chunks of 8 rows x 32 cols; 4 chunks/wave.
  // LDS layout resolves to row-major [128][32] (index 32*r + col).
  auto issue_tile = [&](int t) {
    const float* base = ((t < 2) ? Wc : Wr) + (size_t)m * Hn * Hn +
                        (size_t)((t & 1) * 128) * Hn + ct * 32;
    float* dst = wbuf[t];
#pragma unroll
    for (int q = 0; q < 4; q++) {
      int c = w * 4 + q;
      int r = c * 8 + (lane >> 3);
      gl_lds16(base + (size_t)r * Hn + (lane & 7) * 4, dst + c * 256);
    }
  };
  issue_tile(0);
  issue_tile(1);

  // stage stacked x: row k (0..255) = sum_a comm_in[e][a][k]; row 256+k =
  // prev_hid[e][k]. Thread tid = k; coalesced across threads. These ~288
  // global loads overlap the tile-0/1 DMA latency.
  {
    int k = tid;
#pragma unroll 2
    for (int j = 0; j < En; j++) {
      int e = lst[j];
      float vc = 0.f, vr = 0.f;
      if (e >= 0) {
        const float* cp = comm_in + (size_t)e * (NAGn * Hn) + k;
#pragma unroll
        for (int a = 0; a < NAGn; a++) vc += cp[a * Hn];
        vr = prev_hid[(size_t)e * Hn + k];
      }
      xs[k * XS2 + j] = vc;
      xs[(256 + k) * XS2 + j] = vr;
    }
  }
  issue_tile(2);
  issue_tile(3);

  // ONE full sync: compiler emits s_waitcnt vmcnt(0) lgkmcnt(0) before the
  // barrier -> all 16 DMA chunks/wave landed + xs writes visible, globally.
  __syncthreads();
  __builtin_amdgcn_sched_barrier(0);  // pin: no LDS read hoists above

  int j0 = w * EW;
  int kpar = lane >> 5, col = lane & 31;
  float acc[EW];
#pragma unroll
  for (int i = 0; i < EW; i++) acc[i] = 0.f;

  // no barriers needed below: wbuf tiles are distinct (never rewritten),
  // xs is read-only from here on.
#pragma unroll
  for (int t = 0; t < 4; t++) {
    const float* wb = wbuf[t] + col;
    const float* xb = xs + (size_t)(t * 128 + kpar) * XS2 + j0;
#pragma unroll 8
    for (int kk = 0; kk < 64; kk++) {
      float wv = wb[(2 * kk + kpar) * 32];  // 2-way bank alias only (free)
      float4 xa = *(const float4*)(xb + (2 * kk) * XS2);
      float4 xc = *(const float4*)(xb + (2 * kk) * XS2 + 4);
      acc[0] += xa.x * wv; acc[1] += xa.y * wv;
      acc[2] += xa.z * wv; acc[3] += xa.w * wv;
      acc[4] += xc.x * wv; acc[5] += xc.y * wv;
      acc[6] += xc.z * wv; acc[7] += xc.w * wv;
    }
  }

  // k-parity reduce (lanes l, l+32 hold even/odd-k partials of same col)
#pragma unroll
  for (int i = 0; i < EW; i++) acc[i] += __shfl_xor(acc[i], 32);
  if (lane < 32) {
    int cg = ct * 32 + lane;
    float bsum = bc[m * Hn + cg] + br[m * Hn + cg] + enc_bias[cg];
#pragma unroll
    for (int i = 0; i < EW; i++) {
      int e = lst[j0 + i];
      if (e < 0) continue;
      float h = tanhf(acc[i] + bsum + lut[(size_t)inp[e] * Hn + cg]);
      hid[(size_t)e * Hn + cg] = h;
    }
  }
}

// -------- kernel 2: comm_out = (hid @ Wo + bo)/7; action/baseline ----------
// grid (16 ct[128col], 32 m) = 512 blocks x 256 thr; 65.7 KB LDS -> 2/CU.
// lst is now identical across blocks: block ct owns slots {ct, ct+16}
// (wave 0 / wave 1) -> every example covered exactly once.
__global__ __launch_bounds__(256) void k_outh(
    const float* __restrict__ Wo, const float* __restrict__ bo,
    const float* __restrict__ hid, const int* __restrict__ ids,
    const float* __restrict__ Wa, const float* __restrict__ ba,
    const float* __restrict__ Wb, const float* __restrict__ bb,
    float* __restrict__ aprob, float* __restrict__ bl,
    float* __restrict__ comm_out) {
  int ct = blockIdx.x, m = blockIdx.y;
  int tid = threadIdx.x, w = tid >> 6, lane = tid & 63;
  __shared__ int lst[En];
  __shared__ int segc[8];
  __shared__ alignas(16) float xs[Hn * XS];        // 40 KB
  __shared__ alignas(16) float wbuf[3][16 * 128];  // 24 KB

  int cnt = build_group_det(ids, m, lst, segc, tid);
  if (cnt == 0) return;

  // issue Wo tiles 0 and 1 FIRST: latency hides under staging + softmax.
  const float* wsrc = Wo + (size_t)m * Hn * On + ct * 128;
#pragma unroll
  for (int tt = 0; tt < 2; tt++) {
#pragma unroll
    for (int q = 0; q < 2; q++) {
      int c = w * 2 + q;
      int row = tt * 16 + c * 2 + (lane >> 5);
      gl_lds16(wsrc + (size_t)row * On + (lane & 31) * 4, wbuf[tt] + c * 256);
    }
  }

  // stage x[k][j] from hid (manual transpose; tid = k). 32 coalesced loads.
  for (int j = 0; j < En; j++) {
    int e = lst[j];
    float v = (e >= 0) ? hid[(size_t)e * Hn + tid] : 0.f;
    xs[tid * XS + j] = v;
  }
  // staging barrier: lgkm only (do NOT drain the in-flight Wo DMA).
  asm volatile("s_waitcnt lgkmcnt(0)" ::: "memory");
  __builtin_amdgcn_s_barrier();
  __builtin_amdgcn_sched_barrier(0);  // pin: no xs read hoists above

  // action softmax + baseline for this block's slots: wave0 -> ct,
  // wave1 -> ct+16. Shuffle-only reductions; no block sync inside.
  {
    int jt = (w == 0) ? ct : (w == 1) ? ct + 16 : -1;
    int e = (jt >= 0) ? lst[jt] : -1;
    if (e >= 0) {
      int l = lane, o = l & 15, kk = l >> 4;
      const float* wap = Wa + (size_t)m * Hn * NACTn + l;
      float al = 0.f;
      for (int w16 = 0; w16 < 4; w16++) {
        float wv[16], hv[16];
#pragma unroll
        for (int il = 0; il < 16; il++) wv[il] = wap[(w16 * 16 + il) * 64];
#pragma unroll
        for (int il = 0; il < 16; il++)
          hv[il] = xs[(w16 * 64 + il * 4 + kk) * XS + jt];
#pragma unroll
        for (int il = 0; il < 16; il++) al += wv[il] * hv[il];
      }
      al += __shfl_xor(al, 16);
      al += __shfl_xor(al, 32);
      al += ba[m * NACTn + o];

      float mx = al;
      mx = fmaxf(mx, __shfl_xor(mx, 1));
      mx = fmaxf(mx, __shfl_xor(mx, 2));
      mx = fmaxf(mx, __shfl_xor(mx, 4));
      mx = fmaxf(mx, __shfl_xor(mx, 8));
      float ex = expf(al - mx);
      float sm = ex;
      sm += __shfl_xor(sm, 1);
      sm += __shfl_xor(sm, 2);
      sm += __shfl_xor(sm, 4);
      sm += __shfl_xor(sm, 8);
      if (l < 16) aprob[e * NACTn + l] = ex / sm;

      float pb = 0.f;
      const float* wbp = Wb + (size_t)m * Hn;
      {
        float wv[4], hv[4];
#pragma unroll
        for (int k2 = 0; k2 < 4; k2++) {
          wv[k2] = wbp[l + k2 * 64];
          hv[k2] = xs[(l + k2 * 64) * XS + jt];
        }
#pragma unroll
        for (int k2 = 0; k2 < 4; k2++) pb += wv[k2] * hv[k2];
      }
      pb += __shfl_xor(pb, 1);
      pb += __shfl_xor(pb, 2);
      pb += __shfl_xor(pb, 4);
      pb += __shfl_xor(pb, 8);
      pb += __shfl_xor(pb, 16);
      pb += __shfl_xor(pb, 32);
      if (l == 0) bl[e] = pb + bb[m];
    }
  }

  // Wo stream: 16 tiles x 16 rows; depth-2 prefetch, counted vmcnt.
  int j0 = w * EW;
  float2 acc[EW];
#pragma unroll
  for (int j = 0; j < EW; j++) acc[j] = make_float2(0.f, 0.f);

  for (int t = 0; t < 16; t++) {
    if (t < 14) {
      const float* ws2 = wsrc + (size_t)(t + 2) * 16 * On;
#pragma unroll
      for (int q = 0; q < 2; q++) {
        int c = w * 2 + q;
        int row = c * 2 + (lane >> 5);
        gl_lds16(ws2 + (size_t)row * On + (lane & 31) * 4,
                 wbuf[(t + 2) % 3] + c * 256);
      }
      // own outstanding: tiles t,t+1,t+2 = 6 loads; leave newest 4 in flight.
      asm volatile("s_waitcnt vmcnt(4)" ::: "memory");
    } else if (t == 14) {
      asm volatile("s_waitcnt vmcnt(2)" ::: "memory");
    } else {
      asm volatile("s_waitcnt vmcnt(0)" ::: "memory");
    }
    __builtin_amdgcn_s_barrier();       // all waves' tile-t chunks landed
    __builtin_amdgcn_sched_barrier(0);  // pin: no wbuf read hoists above
    const float* wb = wbuf[t % 3] + lane * 2;
    const float* xb = xs + (size_t)(t * 16) * XS + j0;
#pragma unroll 8
    for (int k = 0; k < 16; k++) {
      float2 wv = *(const float2*)(wb + k * 128);
      float4 xa = *(const float4*)(xb + k * XS);
      float4 xc = *(const float4*)(xb + k * XS + 4);
      acc[0].x += xa.x * wv.x; acc[0].y += xa.x * wv.y;
      acc[1].x += xa.y * wv.x; acc[1].y += xa.y * wv.y;
      acc[2].x += xa.z * wv.x; acc[2].y += xa.z * wv.y;
      acc[3].x += xa.w * wv.x; acc[3].y += xa.w * wv.y;
      acc[4].x += xc.x * wv.x; acc[4].y += xc.x * wv.y;
      acc[5].x += xc.y * wv.x; acc[5].y += xc.y * wv.y;
      acc[6].x += xc.z * wv.x; acc[6].y += xc.z * wv.y;
      acc[7].x += xc.w * wv.x; acc[7].y += xc.w * wv.y;
    }
    // trailing barrier: wbuf[t%3] is the DMA target at iter t+1 ((t+3)%3).
    __builtin_amdgcn_sched_barrier(0);  // pin: no wbuf read sinks below
    __builtin_amdgcn_s_barrier();
    __builtin_amdgcn_sched_barrier(0);
  }
  float2 bv = *(const float2*)(bo + (size_t)m * On + ct * 128 + lane * 2);
  const float inv = 1.f / 7.f;
#pragma unroll
  for (int jj = 0; jj < EW; jj++) {
    int e = lst[j0 + jj];
    if (e < 0) continue;
    float2 o;
    o.x = (acc[jj].x + bv.x) * inv;
    o.y = (acc[jj].y + bv.y) * inv;
    *(float2*)(comm_out + (size_t)e * On + ct * 128 + lane * 2) = o;
  }
}

extern "C" void kernel_launch(void* const* d_in, const int* in_sizes, int n_in,
                              void* d_out, int out_size, void* d_ws, size_t ws_size,
                              hipStream_t stream) {
  const float* comm_in  = (const float*)d_in[0];
  const int*   inp      = (const int*)d_in[1];
  const float* prev_hid = (const float*)d_in[2];
  const int*   ids      = (const int*)d_in[4];
  const float* Wc = (const float*)d_in[5];
  const float* bc = (const float*)d_in[6];
  const float* Wr = (const float*)d_in[7];
  const float* br = (const float*)d_in[8];
  const float* Wa = (const float*)d_in[9];
  const float* ba = (const float*)d_in[10];
  const float* Wb = (const float*)d_in[11];
  const float* bb = (const float*)d_in[12];
  const float* Wo = (const float*)d_in[13];
  const float* bo = (const float*)d_in[14];
  const float* lut      = (const float*)d_in[15];
  const float* enc_bias = (const float*)d_in[16];

  float* out      = (float*)d_out;
  float* aprob    = out;                     // [512,16]
  float* bl       = out + Bn * NACTn;        // [512]
  float* hid      = out + Bn * NACTn + Bn;   // [512,256]
  float* comm_out = hid + Bn * Hn;           // [512,2048]

  (void)d_ws; (void)ws_size;  // acc8 eliminated (R12)

  k_linh<<<dim3(Mn, 8), 256, 0, stream>>>(Wc, Wr, comm_in, prev_hid, ids, inp,
                                          lut, enc_bias, bc, br, hid);
  k_outh<<<dim3(16, Mn), 256, 0, stream>>>(Wo, bo, hid, ids, Wa, ba, Wb, bb,
                                           aprob, bl, comm_out);
}

// Round 7
// 170.656 us; speedup vs baseline: 1.8410x; 1.0585x over previous
//
#include <hip/hip_runtime.h>

// CommNet forward, fp32. B=512, M=32, H=256, NAG=8, NACT=16.
// R15 (resubmit; round-6 bench was an infra failure, kernel never measured).
// Attack k_linh (inferred ~60-90us: 1 blk/CU + 288 serial scalar staging
// loads/thread = latency-bound at 1 wave/SIMD). Changes:
//   k_linh - grid (32 m, 8 ct, 2 jh) = 512 blocks, 16 examples each;
//            LDS 73.2 KB -> 2 blocks/CU. float4 staging (36 loads/thread,
//            deep MLP). W in 2x16KB dbuf, 2 full __syncthreads drains
//            (safe at 2 blk/CU, R7). Same-(m,ct) jh-pairs are 256 apart in
//            linear block id -> same XCD -> W re-read is L2-hit.
//   k_outh - depth-3 Wo prefetch: 4 buffers, prologue issues 4 tiles,
//            steady-state issue AFTER trailing barrier (race-free via
//            barrier), waits vmcnt(6)/(4)/(2)/(0). Poison evicts L3 each
//            iter so Wo is genuinely HBM-sourced; depth-2 was marginal vs
//            ~900cyc HBM latency.
// Kept: deterministic ballot grouping (R14 fix); DMA dest = wave-uniform
// base + lane*16B (R5); sched_barrier pins on raw-barrier clusters (R13/14);
// no launch_bounds min-wave cap (R2); no cooperative launch (R10); no acc8
// round-trip (R12).

constexpr int Bn = 512, Mn = 32, NAGn = 8, Hn = 256, NACTn = 16;
constexpr int On = Hn * NAGn;  // 2048
constexpr int En = 32;         // padded slots/model (counts <= 32: held R1-R14)
constexpr int EW = 8;          // k_outh examples per wave
constexpr int XS = 40;         // k_outh x stride (16B-aligned float4 rows)
constexpr int XS3 = 20;        // k_linh x stride: 20*4=80B, %16==0 -> aligned b128

__device__ __forceinline__ void gl_lds16(const float* g, float* l) {
  __builtin_amdgcn_global_load_lds(
      (const __attribute__((address_space(1))) void*)g,
      (__attribute__((address_space(3))) void*)l, 16, 0, 0);
}

// Deterministic per-model example list: slot j = j-th example (by index e)
// with ids[e]==m. Identical in every block. Returns count. All 256 threads
// must call; two internal __syncthreads.
__device__ __forceinline__ int build_group_det(const int* __restrict__ ids,
                                               int m, int* lst, int* segc,
                                               int tid) {
  int w = tid >> 6, lane = tid & 63;
  if (tid < En) lst[tid] = -1;
  unsigned long long msk[2];
#pragma unroll
  for (int p = 0; p < 2; p++) {
    int i = (w * 2 + p) * 64 + lane;
    msk[p] = __ballot(ids[i] == m);
  }
  if (lane == 0) {
    segc[w * 2 + 0] = __popcll(msk[0]);
    segc[w * 2 + 1] = __popcll(msk[1]);
  }
  __syncthreads();
  int tot = 0;
#pragma unroll
  for (int q = 0; q < 8; q++) tot += segc[q];
#pragma unroll
  for (int p = 0; p < 2; p++) {
    int s = w * 2 + p;
    int pre = 0;
    for (int q = 0; q < 8; q++)
      if (q < s) pre += segc[q];
    int i = s * 64 + lane;
    if ((msk[p] >> lane) & 1ull) {
      int rank = pre + __popcll(msk[p] & ((1ull << lane) - 1ull));
      if (rank < En) lst[rank] = i;
    }
  }
  __syncthreads();
  return tot;
}

// -------- kernel 1: hid = tanh([comm-sum; prev_hid] @ [Wc; Wr] + biases) ----
// grid (32 m, 8 ct[32col], 2 jh[16ex]) = 512 blocks x 256 thr; 73.2 KB -> 2/CU.
__global__ __launch_bounds__(256) void k_linh(
    const float* __restrict__ Wc, const float* __restrict__ Wr,
    const float* __restrict__ comm_in, const float* __restrict__ prev_hid,
    const int* __restrict__ ids, const int* __restrict__ inp,
    const float* __restrict__ lut, const float* __restrict__ enc_bias,
    const float* __restrict__ bc, const float* __restrict__ br,
    float* __restrict__ hid) {
  int m = blockIdx.x, ct = blockIdx.y, jh = blockIdx.z;
  int tid = threadIdx.x, w = tid >> 6, lane = tid & 63;
  __shared__ int lst[En];
  __shared__ int segc[8];
  __shared__ alignas(16) float xs[512 * XS3];      // 40.96 KB: stacked K rows, 16 ex
  __shared__ alignas(16) float wbuf[2][128 * 32];  // 32 KB: 2-tile dbuf

  int cnt = build_group_det(ids, m, lst, segc, tid);
  if (cnt == 0) return;

  // DMA issue for stacked-W tile t (t0,t1 = Wc rows 0..127/128..255;
  // t2,t3 = Wr same). Tile = 16 chunks of 8 rows x 32 cols; 4 chunks/wave.
  // LDS layout resolves to row-major [128][32] (index 32*r + col).
  auto issue_tile = [&](int t, int buf) {
    const float* base = ((t < 2) ? Wc : Wr) + (size_t)m * Hn * Hn +
                        (size_t)((t & 1) * 128) * Hn + ct * 32;
    float* dst = wbuf[buf];
#pragma unroll
    for (int q = 0; q < 4; q++) {
      int c = w * 4 + q;
      int r = c * 8 + (lane >> 3);
      gl_lds16(base + (size_t)r * Hn + (lane & 7) * 4, dst + c * 256);
    }
  };
  issue_tile(0, 0);
  issue_tile(1, 1);

  // float4 staging of this block's 16 slots (local j 0..15 = global slot
  // jh*16 + j). tid -> kq = tid>>2 (16B K-quad), jg = tid&3; j = jg + 4*jj.
  // 36 float4 loads/thread, fully independent -> deep MLP; overlaps W DMA.
  {
    int kq = tid >> 2, jg = tid & 3;
#pragma unroll
    for (int jj = 0; jj < 4; jj++) {
      int j = jg + 4 * jj;
      int e = lst[jh * 16 + j];
      float4 vc = make_float4(0.f, 0.f, 0.f, 0.f);
      float4 vr = vc;
      if (e >= 0) {
        const float4* cp =
            (const float4*)(comm_in + (size_t)e * (NAGn * Hn)) + kq;
#pragma unroll
        for (int a = 0; a < NAGn; a++) {
          float4 t = cp[a * (Hn / 4)];
          vc.x += t.x; vc.y += t.y; vc.z += t.z; vc.w += t.w;
        }
        vr = *((const float4*)(prev_hid + (size_t)e * Hn) + kq);
      }
      int r = kq * 4;
      xs[(r + 0) * XS3 + j] = vc.x;
      xs[(r + 1) * XS3 + j] = vc.y;
      xs[(r + 2) * XS3 + j] = vc.z;
      xs[(r + 3) * XS3 + j] = vc.w;
      xs[(256 + r + 0) * XS3 + j] = vr.x;
      xs[(256 + r + 1) * XS3 + j] = vr.y;
      xs[(256 + r + 2) * XS3 + j] = vr.z;
      xs[(256 + r + 3) * XS3 + j] = vr.w;
    }
  }

  int j0 = w * 4;  // local slot base for this wave (4 slots/wave, 16/block)
  int kpar = lane >> 5, col = lane & 31;
  float acc[4];
#pragma unroll
  for (int i = 0; i < 4; i++) acc[i] = 0.f;

  // two dbuf rounds: {compute tiles 0,1} then {compute tiles 2,3}; each
  // round preceded by a full __syncthreads (vmcnt0+lgkm0 drain: all DMA
  // landed + xs visible). Safe at 2 blocks/CU (R7).
#pragma unroll
  for (int half = 0; half < 2; half++) {
    __syncthreads();
    __builtin_amdgcn_sched_barrier(0);  // pin: no LDS read hoists above
#pragma unroll
    for (int tt = 0; tt < 2; tt++) {
      int t = half * 2 + tt;
      const float* wb = wbuf[tt] + col;
      const float* xb = xs + (size_t)(t * 128 + kpar) * XS3 + j0;
#pragma unroll 8
      for (int kk = 0; kk < 64; kk++) {
        float wv = wb[(2 * kk + kpar) * 32];  // 2-way bank alias only (free)
        float4 xa = *(const float4*)(xb + (2 * kk) * XS3);
        acc[0] += xa.x * wv;
        acc[1] += xa.y * wv;
        acc[2] += xa.z * wv;
        acc[3] += xa.w * wv;
      }
    }
    if (half == 0) {
      // buffers fully consumed by THIS wave; re-issue for tiles 2,3. The
      // next __syncthreads orders all waves' reads before DMA lands.
      __builtin_amdgcn_sched_barrier(0);
      __syncthreads();  // all waves done reading wbuf before re-DMA
      issue_tile(2, 0);
      issue_tile(3, 1);
    }
  }

  // k-parity reduce (lanes l, l+32 hold even/odd-k partials of same col)
#pragma unroll
  for (int i = 0; i < 4; i++) acc[i] += __shfl_xor(acc[i], 32);
  if (lane < 32) {
    int cg = ct * 32 + lane;
    float bsum = bc[m * Hn + cg] + br[m * Hn + cg] + enc_bias[cg];
#pragma unroll
    for (int i = 0; i < 4; i++) {
      int e = lst[jh * 16 + j0 + i];
      if (e < 0) continue;
      float h = tanhf(acc[i] + bsum + lut[(size_t)inp[e] * Hn + cg]);
      hid[(size_t)e * Hn + cg] = h;
    }
  }
}

// -------- kernel 2: comm_out = (hid @ Wo + bo)/7; action/baseline ----------
// grid (16 ct[128col], 32 m) = 512 blocks x 256 thr; 72.9 KB LDS -> 2/CU.
// lst identical across blocks: block ct owns slots {ct, ct+16} (waves 0/1).
__global__ __launch_bounds__(256) void k_outh(
    const float* __restrict__ Wo, const float* __restrict__ bo,
    const float* __restrict__ hid, const int* __restrict__ ids,
    const float* __restrict__ Wa, const float* __restrict__ ba,
    const float* __restrict__ Wb, const float* __restrict__ bb,
    float* __restrict__ aprob, float* __restrict__ bl,
    float* __restrict__ comm_out) {
  int ct = blockIdx.x, m = blockIdx.y;
  int tid = threadIdx.x, w = tid >> 6, lane = tid & 63;
  __shared__ int lst[En];
  __shared__ int segc[8];
  __shared__ alignas(16) float xs[Hn * XS];        // 40 KB
  __shared__ alignas(16) float wbuf[4][16 * 128];  // 32 KB: depth-3 stream

  int cnt = build_group_det(ids, m, lst, segc, tid);
  if (cnt == 0) return;

  // prologue: issue Wo tiles 0..3 (8 chunks/wave in flight); latency hides
  // under staging + softmax.
  const float* wsrc = Wo + (size_t)m * Hn * On + ct * 128;
  auto issue_tile = [&](int t) {
    const float* ws2 = wsrc + (size_t)t * 16 * On;
#pragma unroll
    for (int q = 0; q < 2; q++) {
      int c = w * 2 + q;
      int row = c * 2 + (lane >> 5);
      gl_lds16(ws2 + (size_t)row * On + (lane & 31) * 4,
               wbuf[t & 3] + c * 256);
    }
  };
#pragma unroll
  for (int t = 0; t < 4; t++) issue_tile(t);

  // stage x[k][j] from hid (manual transpose; tid = k). 32 coalesced loads.
  for (int j = 0; j < En; j++) {
    int e = lst[j];
    float v = (e >= 0) ? hid[(size_t)e * Hn + tid] : 0.f;
    xs[tid * XS + j] = v;
  }
  // staging barrier: lgkm only (do NOT drain the in-flight Wo DMA).
  asm volatile("s_waitcnt lgkmcnt(0)" ::: "memory");
  __builtin_amdgcn_s_barrier();
  __builtin_amdgcn_sched_barrier(0);  // pin: no xs read hoists above

  // action softmax + baseline for this block's slots: wave0 -> ct,
  // wave1 -> ct+16. Shuffle-only reductions; no block sync inside.
  {
    int jt = (w == 0) ? ct : (w == 1) ? ct + 16 : -1;
    int e = (jt >= 0) ? lst[jt] : -1;
    if (e >= 0) {
      int l = lane, o = l & 15, kk = l >> 4;
      const float* wap = Wa + (size_t)m * Hn * NACTn + l;
      float al = 0.f;
      for (int w16 = 0; w16 < 4; w16++) {
        float wv[16], hv[16];
#pragma unroll
        for (int il = 0; il < 16; il++) wv[il] = wap[(w16 * 16 + il) * 64];
#pragma unroll
        for (int il = 0; il < 16; il++)
          hv[il] = xs[(w16 * 64 + il * 4 + kk) * XS + jt];
#pragma unroll
        for (int il = 0; il < 16; il++) al += wv[il] * hv[il];
      }
      al += __shfl_xor(al, 16);
      al += __shfl_xor(al, 32);
      al += ba[m * NACTn + o];

      float mx = al;
      mx = fmaxf(mx, __shfl_xor(mx, 1));
      mx = fmaxf(mx, __shfl_xor(mx, 2));
      mx = fmaxf(mx, __shfl_xor(mx, 4));
      mx = fmaxf(mx, __shfl_xor(mx, 8));
      float ex = expf(al - mx);
      float sm = ex;
      sm += __shfl_xor(sm, 1);
      sm += __shfl_xor(sm, 2);
      sm += __shfl_xor(sm, 4);
      sm += __shfl_xor(sm, 8);
      if (l < 16) aprob[e * NACTn + l] = ex / sm;

      float pb = 0.f;
      const float* wbp = Wb + (size_t)m * Hn;
      {
        float wv[4], hv[4];
#pragma unroll
        for (int k2 = 0; k2 < 4; k2++) {
          wv[k2] = wbp[l + k2 * 64];
          hv[k2] = xs[(l + k2 * 64) * XS + jt];
        }
#pragma unroll
        for (int k2 = 0; k2 < 4; k2++) pb += wv[k2] * hv[k2];
      }
      pb += __shfl_xor(pb, 1);
      pb += __shfl_xor(pb, 2);
      pb += __shfl_xor(pb, 4);
      pb += __shfl_xor(pb, 8);
      pb += __shfl_xor(pb, 16);
      pb += __shfl_xor(pb, 32);
      if (l == 0) bl[e] = pb + bb[m];
    }
  }

  // Wo stream: 16 tiles x 16 rows; 4 buffers, depth-3, counted vmcnt.
  // Per-wave outstanding at top of iter t: tiles t..t+3 = 8 chunks (stores
  // from softmax are NEWER than the DMA -> in-order vmcnt keeps this safe).
  int j0 = w * EW;
  float2 acc[EW];
#pragma unroll
  for (int j = 0; j < EW; j++) acc[j] = make_float2(0.f, 0.f);

  for (int t = 0; t < 16; t++) {
    if (t <= 12) {
      asm volatile("s_waitcnt vmcnt(6)" ::: "memory");
    } else if (t == 13) {
      asm volatile("s_waitcnt vmcnt(4)" ::: "memory");
    } else if (t == 14) {
      asm volatile("s_waitcnt vmcnt(2)" ::: "memory");
    } else {
      asm volatile("s_waitcnt vmcnt(0)" ::: "memory");
    }
    __builtin_amdgcn_s_barrier();       // all waves' tile-t chunks landed
    __builtin_amdgcn_sched_barrier(0);  // pin: no wbuf read hoists above
    const float* wb = wbuf[t & 3] + lane * 2;
    const float* xb = xs + (size_t)(t * 16) * XS + j0;
#pragma unroll 8
    for (int k = 0; k < 16; k++) {
      float2 wv = *(const float2*)(wb + k * 128);
      float4 xa = *(const float4*)(xb + k * XS);
      float4 xc = *(const float4*)(xb + k * XS + 4);
      acc[0].x += xa.x * wv.x; acc[0].y += xa.x * wv.y;
      acc[1].x += xa.y * wv.x; acc[1].y += xa.y * wv.y;
      acc[2].x += xa.z * wv.x; acc[2].y += xa.z * wv.y;
      acc[3].x += xa.w * wv.x; acc[3].y += xa.w * wv.y;
      acc[4].x += xc.x * wv.x; acc[4].y += xc.x * wv.y;
      acc[5].x += xc.y * wv.x; acc[5].y += xc.y * wv.y;
      acc[6].x += xc.z * wv.x; acc[6].y += xc.z * wv.y;
      acc[7].x += xc.w * wv.x; acc[7].y += xc.w * wv.y;
    }
    // trailing barrier releases wbuf[t&3]; re-issue for tile t+4 AFTER it
    // (all waves have finished reading) -> race-free, 3-iter issue-to-use.
    __builtin_amdgcn_sched_barrier(0);  // pin: no wbuf read sinks below
    __builtin_amdgcn_s_barrier();
    __builtin_amdgcn_sched_barrier(0);
    if (t <= 11) issue_tile(t + 4);
  }
  float2 bv = *(const float2*)(bo + (size_t)m * On + ct * 128 + lane * 2);
  const float inv = 1.f / 7.f;
#pragma unroll
  for (int jj = 0; jj < EW; jj++) {
    int e = lst[j0 + jj];
    if (e < 0) continue;
    float2 o;
    o.x = (acc[jj].x + bv.x) * inv;
    o.y = (acc[jj].y + bv.y) * inv;
    *(float2*)(comm_out + (size_t)e * On + ct * 128 + lane * 2) = o;
  }
}

extern "C" void kernel_launch(void* const* d_in, const int* in_sizes, int n_in,
                              void* d_out, int out_size, void* d_ws, size_t ws_size,
                              hipStream_t stream) {
  const float* comm_in  = (const float*)d_in[0];
  const int*   inp      = (const int*)d_in[1];
  const float* prev_hid = (const float*)d_in[2];
  const int*   ids      = (const int*)d_in[4];
  const float* Wc = (const float*)d_in[5];
  const float* bc = (const float*)d_in[6];
  const float* Wr = (const float*)d_in[7];
  const float* br = (const float*)d_in[8];
  const float* Wa = (const float*)d_in[9];
  const float* ba = (const float*)d_in[10];
  const float* Wb = (const float*)d_in[11];
  const float* bb = (const float*)d_in[12];
  const float* Wo = (const float*)d_in[13];
  const float* bo = (const float*)d_in[14];
  const float* lut      = (const float*)d_in[15];
  const float* enc_bias = (const float*)d_in[16];

  float* out      = (float*)d_out;
  float* aprob    = out;                     // [512,16]
  float* bl       = out + Bn * NACTn;        // [512]
  float* hid      = out + Bn * NACTn + Bn;   // [512,256]
  float* comm_out = hid + Bn * Hn;           // [512,2048]

  (void)d_ws; (void)ws_size;  // workspace unused (R12+)

  k_linh<<<dim3(Mn, 8, 2), 256, 0, stream>>>(Wc, Wr, comm_in, prev_hid, ids,
                                             inp, lut, enc_bias, bc, br, hid);
  k_outh<<<dim3(16, Mn), 256, 0, stream>>>(Wo, bo, hid, ids, Wa, ba, Wb, bb,
                                           aprob, bl, comm_out);
}